// Round 4
// baseline (92.029 us; speedup 1.0000x reference)
//
#include <hip/hip_runtime.h>
#include <hip/hip_cooperative_groups.h>

namespace cg = cooperative_groups;

// Lovasz-Softmax without sorting (exact up to bin-midpoint error <= 0.5/NB):
//  - ties in the error value don't change the loss (telescoping within
//    equal-error groups)
//  - jaccard is monotone along the sorted order with total variation 1, so
//    binning errors and using midpoints has per-class error <= 4.9e-4 (NB=1024).
// R4: single cooperative kernel (R3 showed ~15us of inter-dispatch overhead:
// 3 dependent graph nodes, each with full-GPU drain/fill). Flow per block:
//   zero ghist slice -> LDS hist -> grid.sync -> atomic flush -> grid.sync
//   -> block 0 scans (6 waves, one class each) and writes the scalar.

constexpr int NCLS = 6;
constexpr int HW   = 512 * 512;
constexpr int NPIX = 8 * HW;
constexpr int NB   = 1024;       // bin width 1/1024 -> loss error <= 4.9e-4
constexpr int NROWS = 2 * NCLS;  // rows 0..5: non-fg (p_c, c!=lab); 6..11: fg (1-p_lab)
constexpr int HIST_WORDS = NROWS * NB;   // 12288 u32 = 48 KB

constexpr int GBLK = 256;        // one block per CU; co-resident (cooperative)
constexpr int GTHR = 1024;

__global__ __launch_bounds__(GTHR) void lovasz_fused(
    const float* __restrict__ logits, const int* __restrict__ labels,
    unsigned* __restrict__ ghist, float* __restrict__ out) {
  cg::grid_group grid = cg::this_grid();
  __shared__ unsigned lh[HIST_WORDS];        // 48 KB

  // ---- zero my slice of the global histogram (48 words/block) ----
  {
    const int per  = HIST_WORDS / GBLK;      // 48
    const int base = blockIdx.x * per;
    for (int i = threadIdx.x; i < per; i += GTHR) ghist[base + i] = 0u;
  }
  for (int i = threadIdx.x; i < HIST_WORDS; i += GTHR) lh[i] = 0u;
  __syncthreads();

  // ---- LDS-private histogram ----
  const int nquads = NPIX / 4;
  for (int q = blockIdx.x * GTHR + threadIdx.x; q < nquads; q += GBLK * GTHR) {
    int n4 = q << 2;
    int b  = n4 >> 18;                       // / HW
    int hw = n4 & (HW - 1);

    int4 lab4 = *reinterpret_cast<const int4*>(labels + n4);
    int labs[4] = {lab4.x, lab4.y, lab4.z, lab4.w};
    if ((lab4.x | lab4.y | lab4.z | lab4.w) == 0) continue;  // all ignored

    float xx[NCLS][4];
    size_t base = ((size_t)b * NCLS) << 18;
#pragma unroll
    for (int c = 0; c < NCLS; ++c) {
      float4 v = *reinterpret_cast<const float4*>(logits + base + ((size_t)c << 18) + hw);
      xx[c][0] = v.x; xx[c][1] = v.y; xx[c][2] = v.z; xx[c][3] = v.w;
    }

#pragma unroll
    for (int j = 0; j < 4; ++j) {
      int lab = labs[j];
      if (lab == 0) continue;                // IGNORE: contributes exactly 0
      float m = xx[0][j];
#pragma unroll
      for (int c = 1; c < NCLS; ++c) m = fmaxf(m, xx[c][j]);
      float e[NCLS];
      float s = 0.f;
#pragma unroll
      for (int c = 0; c < NCLS; ++c) { e[c] = __expf(xx[c][j] - m); s += e[c]; }
      float inv = 1.0f / s;
#pragma unroll
      for (int c = 0; c < NCLS; ++c) {
        float p   = e[c] * inv;
        bool  fg  = (c == lab);
        float err = fg ? 1.0f - p : p;
        int bin = (int)(err * (float)NB);
        bin = bin < 0 ? 0 : (bin > NB - 1 ? NB - 1 : bin);
        int row = fg ? NCLS + c : c;
        atomicAdd(&lh[row * NB + bin], 1u);
      }
    }
  }

  grid.sync();   // all ghist zeroing visible; all blocks' LDS hists complete

  // ---- flush LDS -> global (device-scope atomics) ----
  for (int i = threadIdx.x; i < HIST_WORDS; i += GTHR) {
    unsigned v = lh[i];
    if (v) atomicAdd(&ghist[i], v);
  }

  grid.sync();   // summed histogram visible

  // ---- block 0: 6-wave scan (wave w = class w) + final average ----
  if (blockIdx.x == 0) {
    const int t = threadIdx.x;
    __shared__ double   sloss[NCLS];
    __shared__ unsigned spres[NCLS];
    if (t < 64 * NCLS) {
      const int wave = t >> 6;
      const int lane = t & 63;
      const unsigned* ha = ghist + wave * NB;          // non-fg contributions
      const unsigned* hf = ghist + (NCLS + wave) * NB; // fg contributions
      const int base = NB - 16 - lane * 16;            // lane 0 -> highest bins

      unsigned dn = 0, df = 0;
#pragma unroll
      for (int i = 0; i < 16; ++i) { dn += ha[base + i] + hf[base + i]; df += hf[base + i]; }

      unsigned sn = dn, sf = df;                       // inclusive wave scan
      for (int off = 1; off < 64; off <<= 1) {
        unsigned tn = __shfl_up(sn, off);
        unsigned tf = __shfl_up(sf, off);
        if (lane >= off) { sn += tn; sf += tf; }
      }
      const unsigned total_f = __shfl(sf, 63);         // gts
      unsigned n  = sn - dn;                           // exclusive prefix
      unsigned ff = sf - df;

      double contrib = 0.0;
      if (total_f > 0) {
        const double gts = (double)total_f;
        for (int i = 15; i >= 0; --i) {                // descending within chunk
          unsigned fa  = hf[base + i];
          unsigned dnb = ha[base + i] + fa;
          if (!dnb) continue;
          double ub = gts + (double)n - (double)ff;
          double jb = 1.0 - (gts - (double)ff) / ub;
          n += dnb; ff += fa;
          double ua = gts + (double)n - (double)ff;
          double ja = 1.0 - (gts - (double)ff) / ua;
          contrib += ((double)(base + i) + 0.5) * (1.0 / (double)NB) * (ja - jb);
        }
      }
      for (int off = 32; off > 0; off >>= 1) contrib += __shfl_down(contrib, off);
      if (lane == 0) { sloss[wave] = contrib; spres[wave] = total_f; }
    }
    __syncthreads();
    if (t == 0) {
      double s = 0.0, np = 0.0;
      for (int k = 0; k < NCLS; ++k)
        if (spres[k]) { s += sloss[k]; np += 1.0; }
      out[0] = (float)(s / (np > 0.0 ? np : 1.0));
    }
  }
}

extern "C" void kernel_launch(void* const* d_in, const int* in_sizes, int n_in,
                              void* d_out, int out_size, void* d_ws, size_t ws_size,
                              hipStream_t stream) {
  const float* logits = (const float*)d_in[0];
  const int*   labels = (const int*)d_in[1];
  unsigned*    ghist  = (unsigned*)d_ws;
  float*       outp   = (float*)d_out;

  void* args[] = {(void*)&logits, (void*)&labels, (void*)&ghist, (void*)&outp};
  hipLaunchCooperativeKernel((const void*)lovasz_fused, dim3(GBLK), dim3(GTHR),
                             args, 0, stream);
}